// Round 8
// baseline (208.262 us; speedup 1.0000x reference)
//
#include <hip/hip_runtime.h>

typedef unsigned short u16;
typedef unsigned int u32;
typedef __attribute__((ext_vector_type(8))) short bfrag_t;   // 8 bf16 (4 VGPRs)
typedef __attribute__((ext_vector_type(4))) float accfrag_t; // 4 fp32
typedef __attribute__((ext_vector_type(4))) u32 u32x4;
typedef __attribute__((ext_vector_type(4))) float f32x4;

// ---------- bf16 helpers ----------
__device__ __forceinline__ u16 f2b(float f) {
    u32 u = __float_as_uint(f);
    u32 r = (u + 0x7FFFu + ((u >> 16) & 1u)) >> 16;
    return (u16)r;
}
// pack 2 f32 -> 2 bf16 in one instruction (lo -> bits[15:0], hi -> bits[31:16])
__device__ __forceinline__ u32 pkbf16(float lo, float hi) {
    u32 r;
    asm("v_cvt_pk_bf16_f32 %0, %1, %2" : "=v"(r) : "v"(lo), "v"(hi));
    return r;
}
__device__ __forceinline__ float blo(u32 v) { return __uint_as_float(v << 16); }
__device__ __forceinline__ float bhi(u32 v) { return __uint_as_float(v & 0xffff0000u); }

// ---------- async global->LDS, 16B per lane ----------
__device__ __forceinline__ void load16(const u16* g, u16* l) {
    __builtin_amdgcn_global_load_lds(
        (__attribute__((address_space(1))) void*)(u16*)g,
        (__attribute__((address_space(3))) void*)l,
        16, 0, 0);
}

// ============================================================
// Merged prep: range dispatch, 689 blocks, fully vectorized stores.
//   0..463  : x -> x_tp[8,58,58,256] bf16 (zero-pad border)
//   464..607: W1/W3 frag-pack   608..679: W2 frag-pack   680..688: b2 permute
// d' = rr*256 + c  <->  d = c*9 + rr
// W1f/W3f: [w:8][kc72:72][j:2][lane:64][e:8] ; W2f: [rr:9][w:8][kc:8][j:2][lane:64][e:8]
// ============================================================
__global__ __launch_bounds__(256) void k_prep(
    const float* __restrict__ x, const float* __restrict__ W1,
    const float* __restrict__ W2, const float* __restrict__ W3,
    const float* __restrict__ b2, u16* __restrict__ xtp,
    u16* __restrict__ W1f, u16* __restrict__ W2f,
    u16* __restrict__ W3f, float* __restrict__ b2p) {
    __shared__ __align__(16) char smem[57792];
    const int bid = blockIdx.x;
    const int tid = threadIdx.x;
    if (bid < 464) {             // ---- xtp ----
        const int b = bid / 58;
        const int hp = bid - b * 58;
        u16* rowbase = xtp + (size_t)(b * 58 + hp) * 58 * 256;
        if (hp == 0 || hp == 57) {
            u32x4* p = (u32x4*)rowbase;
            for (int i = tid; i < 58 * 32; i += 256) p[i] = (u32x4)0u;
            return;
        }
        float* lds = (float*)smem;       // [w:56][c:258-pad]
        const int h = hp - 1;
        const float* xb = x + (size_t)b * 802816 + h * 56;
        for (int idx = tid; idx < 256 * 56; idx += 256) {
            int c = idx / 56;
            int w = idx - c * 56;
            lds[w * 258 + c] = xb[c * 3136 + w];
        }
        __syncthreads();
        // border columns w'=0 / w'=57 : 16B vector zero stores
        if (tid < 32) {
            ((u32x4*)rowbase)[tid] = (u32x4)0u;
            ((u32x4*)(rowbase + 57 * 256))[tid] = (u32x4)0u;
        }
        // interior: 1792 chunks of 8 channels; 7 per thread, 16B stores
        for (int it = 0; it < 7; ++it) {
            const int ch = it * 256 + tid;
            const int wp = ch >> 5;          // 0..55
            const int c0 = (ch & 31) * 8;
            const float* lp = lds + wp * 258 + c0;
            f32x4 a = *(const f32x4*)lp;
            f32x4 c = *(const f32x4*)(lp + 4);
            u32x4 v;
            v[0] = pkbf16(a[0], a[1]);
            v[1] = pkbf16(a[2], a[3]);
            v[2] = pkbf16(c[0], c[1]);
            v[3] = pkbf16(c[2], c[3]);
            *(u32x4*)(rowbase + (wp + 1) * 256 + c0) = v;
        }
    } else if (bid < 608) {      // ---- W1 / W3 pack ----
        int b = bid - 464;
        const float* in = b < 72 ? W1 : W3;
        u16* out = b < 72 ? W1f : W3f;
        if (b >= 72) b -= 72;
        const int rrp = b >> 3;          // 0..8
        const int cg = b & 7;            // c-group of 32
        u16* lds1 = (u16*)smem;          // [n:256][q:40-pad]
        for (int cc = 0; cc < 32; ++cc) {
            int d = (cg * 32 + cc) * 9 + rrp;
            lds1[tid * 40 + cc] = f2b(in[d * 256 + tid]);
        }
        __syncthreads();
        const int kc72 = rrp * 8 + cg;
        // 1024 16B-chunks; 4 per thread: one ds_read_b128 + one 16B store
        for (int it = 0; it < 4; ++it) {
            const int ch = it * 256 + tid;
            const int w = ch >> 7;
            const int j = (ch >> 6) & 1;
            const int ln = ch & 63;
            const int n = w * 32 + j * 16 + (ln & 15);
            const int q0 = (ln >> 4) * 8;
            u32x4 v = *(const u32x4*)(lds1 + n * 40 + q0);
            *(u32x4*)(out + (w * 72 + kc72) * 1024 + j * 512 + ln * 8) = v;
        }
    } else if (bid < 680) {      // ---- W2 pack ----
        const int b = bid - 608;
        const int rr = b >> 3;
        const int w = b & 7;
        u16* lds2 = (u16*)smem;          // [dloc:32][k:264-pad]
        for (int s = 0; s < 32; ++s) {
            int li = s * 256 + tid;
            int k = li >> 5, dloc = li & 31;
            lds2[dloc * 264 + k] = f2b(W2[k * 2304 + (w * 32 + dloc) * 9 + rr]);
        }
        __syncthreads();
        u16* ob = W2f + (rr * 8 + w) * 8192;
        for (int it = 0; it < 4; ++it) {
            const int ch = it * 256 + tid;
            const int kc = ch >> 7;
            const int j = (ch >> 6) & 1;
            const int ln = ch & 63;
            const int dloc = j * 16 + (ln & 15);
            const int k0 = kc * 32 + (ln >> 4) * 8;
            u32x4 v = *(const u32x4*)(lds2 + dloc * 264 + k0);
            *(u32x4*)(ob + kc * 1024 + j * 512 + ln * 8) = v;
        }
    } else {                     // ---- b2 permute ----
        int idx = (bid - 680) * 256 + tid;
        if (idx < 2304) b2p[idx] = b2[(idx & 255) * 9 + (idx >> 8)];
    }
}

// ============================================================
// Fused kernel (unchanged from round 7): 392 blocks x 512 threads (8 waves),
// 64 rows/block, column-split 8 x 32. B-frags direct from L2.
// ============================================================
__global__ __launch_bounds__(512, 4) void k_fused(
    const u16* __restrict__ xtp, const u16* __restrict__ W1f,
    const u16* __restrict__ W2f, const u16* __restrict__ W3f,
    const float* __restrict__ b1, const float* __restrict__ b2p,
    const float* __restrict__ b3, float* __restrict__ out) {
    __shared__ __align__(16) u16 As[16384];  // 32KB: t-slab buf0, then h1 [kc:8][row:64][c:32]
    __shared__ __align__(16) u16 Us[16384];  // 32KB: t-slab buf1, then s/u [kc:8][row:64][c:32]

    const int tid = threadIdx.x;
    const int wave = tid >> 6;
    const int lane = tid & 63;
    const int fr = lane & 15;
    const int fq = lane >> 4;
    const int l0 = blockIdx.x * 64;
    const int hi = tid >> 8;

    int roff;
    {
        int l = l0 + ((tid >> 2) & 63);
        int b = l / 3136;
        int rem = l - b * 3136;
        int h = rem / 56;
        int w = rem - h * 56;
        roff = ((b * 58 + h + 1) * 58 + (w + 1)) * 256 + (tid & 3) * 8;
    }
    const int stageOff = (wave & 3) * 512 + lane * 8;
    auto shiftOf = [](int rr) { return ((rr / 3 - 1) * 58 + (rr % 3) - 1) * 256; };
    auto stage = [&](u16* buf, int shift) {
#pragma unroll
        for (int q = 0; q < 4; ++q) {
            const int kc = 2 * q + hi;
            load16(xtp + roff + shift + kc * 32, buf + kc * 2048 + stageOff);
        }
    };

    accfrag_t acc[4][2], accO[4][2];
#pragma unroll
    for (int i = 0; i < 4; ++i)
#pragma unroll
        for (int j = 0; j < 2; ++j) {
            acc[i][j] = (accfrag_t)0.f;
            accO[i][j] = (accfrag_t)0.f;
        }

    // ---------------- phase 1: h1 = relu(t @ W1 + b1), double-buffered ----
    const u16* w1p = W1f + wave * 73728 + lane * 8;
    stage(As, shiftOf(0));
    for (int rr = 0; rr < 9; ++rr) {
        u16* cur = (rr & 1) ? Us : As;
        u16* nxt = (rr & 1) ? As : Us;
        __syncthreads();   // cur slab visible (and nxt's readers from rr-1 done)
        if (rr < 8) stage(nxt, shiftOf(rr + 1));   // in flight during MFMA
#pragma unroll
        for (int kc = 0; kc < 8; ++kc) {
            bfrag_t bf[2], af[4];
#pragma unroll
            for (int j = 0; j < 2; ++j)
                bf[j] = *(const bfrag_t*)(w1p + ((rr * 8 + kc) * 2 + j) * 512);
#pragma unroll
            for (int i = 0; i < 4; ++i)
                af[i] = *(const bfrag_t*)(cur + kc * 2048 + (i * 16 + fr) * 32 + fq * 8);
#pragma unroll
            for (int i = 0; i < 4; ++i)
#pragma unroll
                for (int j = 0; j < 2; ++j)
                    acc[i][j] = __builtin_amdgcn_mfma_f32_16x16x32_bf16(
                        af[i], bf[j], acc[i][j], 0, 0, 0);
        }
    }
    // h1 epilogue: relu, pair-pack (cvt_pk), chunk-major into As
    __syncthreads();
#pragma unroll
    for (int i = 0; i < 4; ++i) {
#pragma unroll
        for (int j = 0; j < 2; ++j) {
            const float bv = b1[wave * 32 + j * 16 + fr];
#pragma unroll
            for (int r = 0; r < 4; ++r) {
                float v = acc[i][j][r] + bv;
                v = v > 0.f ? v : 0.f;
                const float vh = __shfl_down(v, 1);
                if (!(lane & 1))
                    *(u32*)&As[wave * 2048 + (i * 16 + fq * 4 + r) * 32 + j * 16 + fr] =
                        pkbf16(v, vh);
            }
        }
    }
    __syncthreads();

    // ---------------- phase 2: per rr slab ----------------
    const u16* w3p = W3f + wave * 73728 + lane * 8;
    for (int rr = 0; rr < 9; ++rr) {
        const int shift = shiftOf(rr);
        u32x4 tvreg[4];
#pragma unroll
        for (int q = 0; q < 4; ++q) {
            const int kc = 2 * q + hi;
            tvreg[q] = *(const u32x4*)(xtp + roff + shift + kc * 32);
        }
        // 2a: z = h1 @ W2slab (K=256, barrier-free)
#pragma unroll
        for (int i = 0; i < 4; ++i)
#pragma unroll
            for (int j = 0; j < 2; ++j) acc[i][j] = (accfrag_t)0.f;
        const u16* w2p = W2f + (rr * 8 + wave) * 8192 + lane * 8;
#pragma unroll
        for (int kc = 0; kc < 8; ++kc) {
            bfrag_t bf[2], af[4];
#pragma unroll
            for (int j = 0; j < 2; ++j)
                bf[j] = *(const bfrag_t*)(w2p + (kc * 2 + j) * 512);
#pragma unroll
            for (int i = 0; i < 4; ++i)
                af[i] = *(const bfrag_t*)(As + kc * 2048 + (i * 16 + fr) * 32 + fq * 8);
#pragma unroll
            for (int i = 0; i < 4; ++i)
#pragma unroll
                for (int j = 0; j < 2; ++j)
                    acc[i][j] = __builtin_amdgcn_mfma_f32_16x16x32_bf16(
                        af[i], bf[j], acc[i][j], 0, 0, 0);
        }
        __syncthreads();  // prev rr's 2b reads of Us done
        // sigmoid pair-pack -> Us
#pragma unroll
        for (int i = 0; i < 4; ++i) {
#pragma unroll
            for (int j = 0; j < 2; ++j) {
                const float bv = b2p[rr * 256 + wave * 32 + j * 16 + fr];
#pragma unroll
                for (int r = 0; r < 4; ++r) {
                    const float z = acc[i][j][r] + bv;
                    const float s = __builtin_amdgcn_rcpf(1.f + __expf(-z));
                    const float sh = __shfl_down(s, 1);
                    if (!(lane & 1))
                        *(u32*)&Us[wave * 2048 + (i * 16 + fq * 4 + r) * 32 + j * 16 + fr] =
                            pkbf16(s, sh);
                }
            }
        }
        __syncthreads();  // s visible
        // u = t * s  (dword math; each 16B chunk owned by one thread)
#pragma unroll
        for (int q = 0; q < 4; ++q) {
            const int kc = 2 * q + hi;
            const int idx = kc * 2048 + ((tid * 8) & 2047);
            u32x4 sv = *(const u32x4*)(Us + idx);
            u32x4 rv;
#pragma unroll
            for (int e = 0; e < 4; ++e)
                rv[e] = pkbf16(blo(sv[e]) * blo(tvreg[q][e]),
                               bhi(sv[e]) * bhi(tvreg[q][e]));
            *(u32x4*)(Us + idx) = rv;
        }
        __syncthreads();  // u visible
        // 2b: accO += u @ W3slab (K=256)
#pragma unroll
        for (int kc = 0; kc < 8; ++kc) {
            bfrag_t bf[2], af[4];
#pragma unroll
            for (int j = 0; j < 2; ++j)
                bf[j] = *(const bfrag_t*)(w3p + ((rr * 8 + kc) * 2 + j) * 512);
#pragma unroll
            for (int i = 0; i < 4; ++i)
                af[i] = *(const bfrag_t*)(Us + kc * 2048 + (i * 16 + fr) * 32 + fq * 8);
#pragma unroll
            for (int i = 0; i < 4; ++i)
#pragma unroll
                for (int j = 0; j < 2; ++j)
                    accO[i][j] = __builtin_amdgcn_mfma_f32_16x16x32_bf16(
                        af[i], bf[j], accO[i][j], 0, 0, 0);
        }
    }

    // ---------------- final epilogue: out = accO + b3 ----------------
#pragma unroll
    for (int i = 0; i < 4; ++i) {
#pragma unroll
        for (int j = 0; j < 2; ++j) {
            const int col = wave * 32 + j * 16 + fr;
            const float bv = b3[col];
#pragma unroll
            for (int r = 0; r < 4; ++r) {
                const float v = accO[i][j][r] + bv;
                const float vh = __shfl_down(v, 1);
                if (!(lane & 1)) {
                    float2 st = make_float2(v, vh);
                    *(float2*)(out + (size_t)(l0 + i * 16 + fq * 4 + r) * 256 + col) = st;
                }
            }
        }
    }
}

extern "C" void kernel_launch(void* const* d_in, const int* in_sizes, int n_in,
                              void* d_out, int out_size, void* d_ws, size_t ws_size,
                              hipStream_t stream) {
    const float* x  = (const float*)d_in[0];
    const float* W1 = (const float*)d_in[1];
    const float* b1 = (const float*)d_in[2];
    const float* W2 = (const float*)d_in[3];
    const float* b2 = (const float*)d_in[4];
    const float* W3 = (const float*)d_in[5];
    const float* b3 = (const float*)d_in[6];
    float* out = (float*)d_out;

    char* ws = (char*)d_ws;
    u16* xtp = (u16*)ws;  ws += (size_t)8 * 58 * 58 * 256 * 2;
    u16* W1f = (u16*)ws;  ws += (size_t)589824 * 2;
    u16* W2f = (u16*)ws;  ws += (size_t)589824 * 2;
    u16* W3f = (u16*)ws;  ws += (size_t)589824 * 2;
    float* b2p = (float*)ws;

    k_prep<<<689, 256, 0, stream>>>(x, W1, W2, W3, b2, xtp, W1f, W2f, W3f, b2p);
    k_fused<<<392, 512, 0, stream>>>(xtp, W1f, W2f, W3f, b1, b2p, b3, out);
}